// Round 2
// baseline (186.345 us; speedup 1.0000x reference)
//
#include <hip/hip_runtime.h>
#include <math.h>

// ---------------------------------------------------------------------------
// HADCommNetwork forward — fused enc+qkv, composite weights, fat-tile flash.
// B=64, N=512, OBS=128, H=256, M=128, ACT=16, T=32768.
// Identity: msg has no activation and only feeds K,V =>
//   K = enc@(Wm·Wk)+(bm·Wk+bk), V = enc@(Wm·Wv)+(bm·Wv+bv)  (msg eliminated).
// r11: enc+qkv fused into one kernel (enc tile stays in LDS as the qkv
// A-operand; imp computed block-locally via LDS atomics — no global round
// trip, no 3x enc re-read). wprod folded into prep_all reading the f32
// weights directly (dependency-free). 4 launches:
//   prep_all(+wprod) | encqkv | flash4b | x+heads
// ---------------------------------------------------------------------------

typedef __attribute__((ext_vector_type(8))) short short8;
typedef __attribute__((ext_vector_type(4))) float f32x4;

#define RSQRT_D 0.08838834764831843f  // 1/sqrt(128)
#define MFMA __builtin_amdgcn_mfma_f32_16x16x32_bf16

__device__ __forceinline__ unsigned short f2bf(float f) {
  union { float f; unsigned u; } v; v.f = f;
  return (unsigned short)((v.u + 0x7FFFu + ((v.u >> 16) & 1u)) >> 16);
}
__device__ __forceinline__ float bf2f(unsigned short h) {
  union { unsigned u; float f; } v; v.u = ((unsigned)h) << 16;
  return v.f;
}
__device__ __forceinline__ unsigned pack2(float a, float b) {
  return (unsigned)f2bf(a) | ((unsigned)f2bf(b) << 16);
}
__device__ __forceinline__ short8 ld8(const unsigned short* p) {
  return *(const short8*)p;
}
__device__ __forceinline__ void gl16(const unsigned short* g,
                                     unsigned short* l) {
  __builtin_amdgcn_global_load_lds(
      (const __attribute__((address_space(1))) unsigned int*)(const void*)g,
      (__attribute__((address_space(3))) unsigned int*)(void*)l, 16, 0, 0);
}

// ---------------- prep: weights + obs + output init + composite wprod ----------------
// blocks 0..672: weight transposes/packs (172160 elems)
// blocks 673..2720: obs prep (16 tokens/block)
// blocks 2721..4896: logits/value init
// blocks 4897..4904: composite Wqkv rows 128..383 via MFMA from f32 sources
// block  4905: bqkv rows 128..383 tail
__global__ __launch_bounds__(256) void prep_all(
    const float* __restrict__ obs, const float* __restrict__ We,
    const float* __restrict__ Wq, const float* __restrict__ Wk,
    const float* __restrict__ Wv, const float* __restrict__ Wp,
    const float* __restrict__ Wc, const float* __restrict__ Wn,
    const float* __restrict__ Wb, const float* __restrict__ bc,
    const float* __restrict__ bn, const float* __restrict__ bb,
    const float* __restrict__ Wa, const float* __restrict__ Wcr,
    const float* __restrict__ ba, const float* __restrict__ bcr,
    const float* __restrict__ bq, const float* __restrict__ bk,
    const float* __restrict__ bv, unsigned short* __restrict__ WeT,
    unsigned short* __restrict__ Wqkv, unsigned short* __restrict__ WpT,
    unsigned short* __restrict__ WaCrT, float* __restrict__ bqkv,
    unsigned short* __restrict__ obs_bf, unsigned short* __restrict__ As,
    unsigned short* __restrict__ Bs, float* __restrict__ logits,
    float* __restrict__ value) {
  const int bid = blockIdx.x, tid = threadIdx.x;
  if (bid < 673) {
    int idx = bid * 256 + tid;
    if (idx < 32768) {                 // WeT[n 256][k 128]
      int n = idx >> 7, k = idx & 127;
      WeT[idx] = f2bf(We[k * 256 + n]);
    } else if (idx < 65536) {          // Wqkv rows 0..127: WqT[n 128][k 256]
      int i = idx - 32768;
      int n = i >> 8, k = i & 255;
      Wqkv[i] = f2bf(Wq[k * 128 + n]);
    } else if (idx < 163840) {         // WpT[n 256][k 384]
      int i = idx - 65536;
      int n = i / 384, k = i - n * 384;
      WpT[i] = f2bf(Wp[k * 256 + n]);
    } else if (idx < 172032) {         // WaCrT[32][256]
      int i = idx - 163840;
      int n = i >> 8, k = i & 255;
      float v = (n < 16) ? Wa[k * 16 + n] : (n == 16) ? Wcr[k] : 0.f;
      WaCrT[i] = f2bf(v);
    } else if (idx < 172160) {
      int i = idx - 172032;
      bqkv[i] = bq[i];
    }
  } else if (bid < 2721) {
    // obs prep: 16 tokens/block (4 per wave)
    const int wave = tid >> 6, lane = tid & 63;
    const int t0 = (bid - 673) * 16 + wave * 4;
#pragma unroll
    for (int it = 0; it < 4; ++it) {
      int t = t0 + it;
      const float* row = obs + (size_t)t * 128;
      float2 o = *(const float2*)(row + lane * 2);
      float s2 = o.x * o.x + o.y * o.y;
#pragma unroll
      for (int off = 1; off < 64; off <<= 1) s2 += __shfl_xor(s2, off);
      float inv = 1.f / (sqrtf(s2) + 1e-8f);
      ((unsigned*)obs_bf)[(size_t)t * 64 + lane] = pack2(o.x, o.y);
      ((unsigned*)As)[(size_t)t * 128 + 64 + lane] =
          pack2(o.x * 0.5f * inv, o.y * 0.5f * inv);
      ((unsigned*)Bs)[(size_t)t * 128 + 64 + lane] =
          pack2(o.x * inv, o.y * inv);
    }
  } else if (bid < 4897) {
    int i = (bid - 2721) * 256 + tid;
    if (i < 524288) logits[i] = ba[i & 15];
    else value[i - 524288] = bcr[0];
  } else if (bid < 4905) {
    // composite Wqkv rows 128..383 = Wkv @ Wm^T via MFMA, f32 sources inline
    const int wb = bid - 4897;
    const int lane = tid & 63, wave = tid >> 6;
    const int quad = lane >> 4, l16 = lane & 15;
    const int r0 = wb * 32;
    f32x4 acc[2][4];
#pragma unroll
    for (int i = 0; i < 2; ++i)
#pragma unroll
      for (int j = 0; j < 4; ++j) acc[i][j] = (f32x4){0.f, 0.f, 0.f, 0.f};
#pragma unroll
    for (int kc = 0; kc < 4; ++kc) {
      short8 af[2], bf[4];
#pragma unroll
      for (int i = 0; i < 2; ++i) {
        int n = r0 + i * 16 + l16;
        const float* src = (n < 128) ? (Wk + n) : (Wv + (n - 128));
        short8 v;
#pragma unroll
        for (int e = 0; e < 8; ++e)
          v[e] = (short)f2bf(src[(size_t)(kc * 32 + quad * 8 + e) * 128]);
        af[i] = v;
      }
#pragma unroll
      for (int j = 0; j < 4; ++j) {
        int h = wave * 64 + j * 16 + l16;
        int m0 = kc * 32 + quad * 8;
        const float* p = (m0 < 32)   ? (Wc + (size_t)h * 32 + m0)
                       : (m0 < 96)   ? (Wn + (size_t)h * 64 + (m0 - 32))
                                     : (Wb + (size_t)h * 32 + (m0 - 96));
        short8 v;
#pragma unroll
        for (int e = 0; e < 8; ++e) v[e] = (short)f2bf(p[e]);
        bf[j] = v;
      }
#pragma unroll
      for (int i = 0; i < 2; ++i)
#pragma unroll
        for (int j = 0; j < 4; ++j)
          acc[i][j] = MFMA(af[i], bf[j], acc[i][j], 0, 0, 0);
    }
#pragma unroll
    for (int i = 0; i < 2; ++i) {
      const int row = r0 + i * 16 + quad * 4;
#pragma unroll
      for (int j = 0; j < 4; ++j) {
        const int col = wave * 64 + j * 16 + l16;
#pragma unroll
        for (int r = 0; r < 4; ++r)
          Wqkv[(size_t)(128 + row + r) * 256 + col] = f2bf(acc[i][j][r]);
      }
    }
  } else {
    // bqkv rows 128..383 (bf16-rounded Wkv to match MFMA-path numerics)
    int i = tid;
    float acc = (i < 128) ? bk[i] : bv[i - 128];
    for (int m = 0; m < 128; ++m) {
      float bmv = (m < 32) ? bc[m] : (m < 96) ? bn[m - 32] : bb[m - 96];
      float w = (i < 128) ? Wk[(size_t)m * 128 + i]
                          : Wv[(size_t)m * 128 + (i - 128)];
      acc += bmv * bf2f(f2bf(w));
    }
    bqkv[128 + i] = acc;
  }
}

// ---------------- encqkv: fused enc GEMM + imp + qkv GEMM ----------------
// 512 blocks x 256 thr. bm0 = bid*64 (64-row tile).
// Phase 1: enc[64][256] = relu(obs@We+be), A/B staged single-shot (80KB).
// Phase 2: acc -> enc_lds (Pp-swizzle, qkv A-operand) + global enc + imp (LDS).
// Phase 3: 3 N-tiles of qkv from enc_lds, Wqkv streamed 64-K dbuf chunks.
__global__ __launch_bounds__(256, 2) void encqkv(
    const unsigned short* __restrict__ obs_bf,
    const unsigned short* __restrict__ WeT, const float* __restrict__ be,
    const float* __restrict__ Wi, const float* __restrict__ bi,
    const unsigned short* __restrict__ Wqkv, const float* __restrict__ bqkv,
    unsigned short* __restrict__ enc, unsigned short* __restrict__ As,
    unsigned short* __restrict__ Bs, unsigned short* __restrict__ vT) {
  __shared__ char smem[81920];
  unsigned short* Asr = (unsigned short*)smem;             // ph1: [64][128] 16KB
  unsigned short* Bsr = (unsigned short*)(smem + 16384);   // ph1: [256][128] 64KB
  unsigned short* encl = (unsigned short*)smem;            // ph2+: 2x[64][128] 32KB
  unsigned short* Bq = (unsigned short*)(smem + 32768);    // ph3: dbuf 2x16KB
  float* imp_lds = (float*)(smem + 65536);                 // 64 floats
  const int tid = threadIdx.x, lane = tid & 63, wave = tid >> 6;
  const int quad = lane >> 4, l16 = lane & 15;
  const int bm0 = blockIdx.x * 64;

  // ---- phase 1: stage obs tile (4 rounds) + full WeT (16 rounds) ----
#pragma unroll
  for (int it = 0; it < 4; ++it) {
    int c = it * 256 + tid;
    int row = c >> 4, ch = c & 15;
    gl16(obs_bf + (size_t)(bm0 + row) * 128 + ((ch ^ (row & 15)) << 3),
         Asr + it * 2048 + wave * 512);
  }
#pragma unroll
  for (int it = 0; it < 16; ++it) {
    int c = it * 256 + tid;
    int row = c >> 4, ch = c & 15;
    gl16(WeT + (size_t)row * 128 + ((ch ^ (row & 15)) << 3),
         Bsr + it * 2048 + wave * 512);
  }
  __syncthreads();

  f32x4 acc[4][4];
#pragma unroll
  for (int i = 0; i < 4; ++i)
#pragma unroll
    for (int j = 0; j < 4; ++j) acc[i][j] = (f32x4){0.f, 0.f, 0.f, 0.f};
#pragma unroll
  for (int ks = 0; ks < 4; ++ks) {
    short8 af[4], bf[4];
#pragma unroll
    for (int mi = 0; mi < 4; ++mi) {
      int row = mi * 16 + l16;
      af[mi] = *(const short8*)&Asr[row * 128 + (((ks * 4 + quad) ^ (row & 15)) << 3)];
    }
#pragma unroll
    for (int ni = 0; ni < 4; ++ni) {
      int row = wave * 64 + ni * 16 + l16;
      bf[ni] = *(const short8*)&Bsr[row * 128 + (((ks * 4 + quad) ^ (row & 15)) << 3)];
    }
#pragma unroll
    for (int mi = 0; mi < 4; ++mi)
#pragma unroll
      for (int ni = 0; ni < 4; ++ni)
        acc[mi][ni] = MFMA(af[mi], bf[ni], acc[mi][ni], 0, 0, 0);
  }
  __syncthreads();  // all Asr/Bsr reads complete; LDS reusable

  if (tid < 64) imp_lds[tid] = 0.f;
  __syncthreads();  // imp zeroed before atomics

  // ---- phase 3 prefetch: first Wqkv chunk (ct=0, kt=0) into Bq[0] ----
  {
#pragma unroll
    for (int i = 0; i < 4; ++i) {
      int row = i * 32 + (tid >> 3);
      gl16(Wqkv + (size_t)row * 256 + (((tid & 7) ^ (row & 7)) << 3),
           Bq + i * 2048 + wave * 512);
    }
  }

  // ---- phase 2: acc -> enc_lds + global enc + block-local imp ----
  const float bi0 = bi[0];
#pragma unroll
  for (int mi = 0; mi < 4; ++mi) {
    const int rowl = mi * 16 + quad * 4;
    float ip[4] = {0.f, 0.f, 0.f, 0.f};
#pragma unroll
    for (int ni = 0; ni < 4; ++ni) {
      const int col = wave * 64 + ni * 16 + l16;
      const float bvv = be[col], wv = Wi[col];
      const int kh = col >> 7, ic = col & 127;
#pragma unroll
      for (int r = 0; r < 4; ++r) {
        const int row = rowl + r;
        float v = fmaxf(acc[mi][ni][r] + bvv, 0.f);
        enc[(size_t)(bm0 + row) * 256 + col] = f2bf(v);
        encl[kh * 8192 + row * 128 + (((ic >> 3) ^ (row & 15)) << 3) + (ic & 7)] =
            f2bf(v);
        ip[r] += v * wv;
      }
    }
#pragma unroll
    for (int r = 0; r < 4; ++r) {
#pragma unroll
      for (int off = 1; off < 16; off <<= 1) ip[r] += __shfl_xor(ip[r], off);
    }
    if (l16 == 0) {
#pragma unroll
      for (int r = 0; r < 4; ++r) atomicAdd(&imp_lds[rowl + r], ip[r]);
    }
  }
  __syncthreads();  // encl + imp ready; Bq[0] landed (vmcnt drained)

  // ---- phase 3: qkv = enc_lds @ Wqkv^T, 3 N-tiles, 64-K dbuf chunks ----
  const int wm = wave & 1, wn = wave >> 1;
  for (int ct = 0; ct < 3; ++ct) {
    f32x4 a2[2][4];
#pragma unroll
    for (int i = 0; i < 2; ++i)
#pragma unroll
      for (int j = 0; j < 4; ++j) a2[i][j] = (f32x4){0.f, 0.f, 0.f, 0.f};
#pragma unroll
    for (int kt = 0; kt < 4; ++kt) {
      // prefetch next chunk (next kt, or next ct's kt=0)
      if (kt < 3 || ct < 2) {
        const int nct = (kt < 3) ? ct : ct + 1;
        const int nkt = (kt < 3) ? kt + 1 : 0;
        const int nbo = ((kt + 1) & 1) * 8192;
#pragma unroll
        for (int i = 0; i < 4; ++i) {
          int row = i * 32 + (tid >> 3);
          gl16(Wqkv + (size_t)(nct * 128 + row) * 256 + nkt * 64 +
                   (((tid & 7) ^ (row & 7)) << 3),
               Bq + nbo + i * 2048 + wave * 512);
        }
      }
      const int bo = (kt & 1) * 8192;
#pragma unroll
      for (int ks2 = 0; ks2 < 2; ++ks2) {
        const int kc = kt * 2 + ks2;
        const int kh = kc >> 2, c4 = kc & 3;
        short8 af2[2], bf2[4];
#pragma unroll
        for (int mi = 0; mi < 2; ++mi) {
          int row = wm * 32 + mi * 16 + l16;
          af2[mi] = *(const short8*)&encl[kh * 8192 + row * 128 +
                                          (((c4 * 4 + quad) ^ (row & 15)) << 3)];
        }
#pragma unroll
        for (int ni = 0; ni < 4; ++ni) {
          int row = wn * 64 + ni * 16 + l16;
          bf2[ni] = *(const short8*)&Bq[bo + row * 64 +
                                        (((ks2 * 4 + quad) ^ (row & 7)) << 3)];
        }
#pragma unroll
        for (int mi = 0; mi < 2; ++mi)
#pragma unroll
          for (int ni = 0; ni < 4; ++ni)
            a2[mi][ni] = MFMA(af2[mi], bf2[ni], a2[mi][ni], 0, 0, 0);
      }
      __syncthreads();
    }

    // epilogue for this N-tile
#pragma unroll
    for (int mi = 0; mi < 2; ++mi) {
      const int rowl = wm * 32 + mi * 16 + quad * 4;
      const int rowb = bm0 + rowl;
      float sg[4];
      if (ct < 2) {
        const float mult = (ct == 0) ? RSQRT_D : 1.0f;
#pragma unroll
        for (int r = 0; r < 4; ++r)
          sg[r] = mult / (1.f + __expf(-(imp_lds[rowl + r] + bi0)));
      }
#pragma unroll
      for (int ni = 0; ni < 4; ++ni) {
        const int col = wn * 64 + ni * 16 + l16;
        const float bvv = bqkv[ct * 128 + col];
        if (ct == 0) {
#pragma unroll
          for (int r = 0; r < 4; ++r)
            As[(size_t)(rowb + r) * 256 + col] =
                f2bf((a2[mi][ni][r] + bvv) * sg[r]);
        } else if (ct == 1) {
#pragma unroll
          for (int r = 0; r < 4; ++r)
            Bs[(size_t)(rowb + r) * 256 + col] =
                f2bf((a2[mi][ni][r] + bvv) * sg[r]);
        } else {
          uint2 o;
          o.x = pack2(a2[mi][ni][0] + bvv, a2[mi][ni][1] + bvv);
          o.y = pack2(a2[mi][ni][2] + bvv, a2[mi][ni][3] + bvv);
          *(uint2*)(vT + ((size_t)(rowb >> 9) * 128 + col) * 512 +
                    (rowb & 511)) = o;
        }
      }
    }
  }
}

// ---------------- flash4b: q-tile 64, 512 threads, single-pass softmax ----------------
// 512 blocks: b = id&63 (XCD-local), qt = id>>6 (8 q-tiles of 64).
// 8 waves: wm = wave&3 (16-row group), wn = wave>>2 (64-key half of staged 128).
// QK^T: 16 pipelined chunks (128 keys x 64 dims, 16 KB), dbuf in same 32 KB Ub.
__global__ __launch_bounds__(512, 4) void flash4b(
    const unsigned short* __restrict__ As, const unsigned short* __restrict__ Bs,
    const unsigned short* __restrict__ vT, unsigned short* __restrict__ agg) {
  __shared__ unsigned short Ub[16384];  // 32 KB
  __shared__ unsigned short Pp[8192];   // 16 KB (64 q x 128 keys)
  __shared__ float redm[2][64];
  __shared__ float reds[2][64];
  const int tid = threadIdx.x, lane = tid & 63, wave = tid >> 6;
  const int quad = lane >> 4, l16 = lane & 15;
  const int wm = wave & 3, wn = wave >> 2;
  const int b = blockIdx.x & 63;
  const int qt = blockIdx.x >> 6;
  const size_t tok0 = (size_t)b * 512 + qt * 64;
  const int srow = tid >> 4, slc = tid & 15;  // PV staging: 32 rows/iter
  const int qr8 = tid >> 3, ql8 = tid & 7;    // QK^T staging: 64 rows/round

  short8 af[8];
#pragma unroll
  for (int kc = 0; kc < 8; ++kc)
    af[kc] = ld8(As + (tok0 + wm * 16 + l16) * 256 + kc * 32 + quad * 8);

  f32x4 s[4][4];
#pragma unroll
  for (int kt = 0; kt < 4; ++kt)
#pragma unroll
    for (int nt = 0; nt < 4; ++nt) s[kt][nt] = (f32x4){0.f, 0.f, 0.f, 0.f};

  // ---- QK^T over all 512 keys: pipelined chunk c = (kt<<2)|dq ----
  auto qstage = [&](int c) {
    const int kt_ = c >> 2, dq_ = c & 3;
#pragma unroll
    for (int r2 = 0; r2 < 2; ++r2) {
      int row = r2 * 64 + qr8;
      gl16(Bs + ((size_t)b * 512 + kt_ * 128 + row) * 256 + dq_ * 64 +
               ((ql8 ^ (row & 7)) << 3),
           Ub + (c & 1) * 8192 + r2 * 4096 + wave * 512);
    }
  };
  qstage(0);
  __syncthreads();
#pragma unroll 16
  for (int c = 0; c < 16; ++c) {
    if (c < 15) qstage(c + 1);
    const int kt = c >> 2, dq = c & 3;
    const int ub0 = (c & 1) * 8192;
#pragma unroll
    for (int kk2 = 0; kk2 < 2; ++kk2) {
      short8 bfr[4];
#pragma unroll
      for (int nt = 0; nt < 4; ++nt) {
        int rr = wn * 64 + nt * 16 + l16;
        bfr[nt] = *(const short8*)&Ub[ub0 + rr * 64 +
                                      (((kk2 * 2 + quad) ^ (rr & 7)) << 3)];
      }
#pragma unroll
      for (int nt = 0; nt < 4; ++nt)
        s[kt][nt] = MFMA(af[dq * 2 + kk2], bfr[nt], s[kt][nt], 0, 0, 0);
    }
    __syncthreads();
  }

  // ---- exact softmax (rows = wm*16 + quad*4 + r) ----
  const int rbase = wm * 16 + quad * 4;
  float mt[4];
#pragma unroll
  for (int r = 0; r < 4; ++r) {
    float mv = -1e30f;
#pragma unroll
    for (int kt = 0; kt < 4; ++kt)
#pragma unroll
      for (int nt = 0; nt < 4; ++nt) mv = fmaxf(mv, s[kt][nt][r]);
#pragma unroll
    for (int off = 1; off < 16; off <<= 1) mv = fmaxf(mv, __shfl_xor(mv, off));
    mt[r] = mv;
  }
  if (l16 == 0) {
#pragma unroll
    for (int r = 0; r < 4; ++r) redm[wn][rbase + r] = mt[r];
  }
  __syncthreads();
  float lsum[4];
#pragma unroll
  for (int r = 0; r < 4; ++r) {
    float mfull = fmaxf(mt[r], redm[1 ^ wn][rbase + r]);
    float sum = 0.f;
#pragma unroll
    for (int kt = 0; kt < 4; ++kt)
#pragma unroll
      for (int nt = 0; nt < 4; ++nt) {
        float p = __expf(s[kt][nt][r] - mfull);
        s[kt][nt][r] = p;
        sum += p;
      }
#pragma unroll
    for (int off = 1; off < 16; off <<= 1) sum += __shfl_xor(sum, off);
    lsum[r] = sum;
  }
  if (l16 == 0) {
#pragma unroll
    for (int r = 0; r < 4; ++r) reds[wn][rbase + r] = lsum[r];
  }
  __syncthreads();
  float linv[4];
#pragma unroll
  for (int r = 0; r < 4; ++r)
    linv[r] = 1.0f / (lsum[r] + reds[1 ^ wn][rbase + r]);

  // ---- PV over 4 key chunks ----
  f32x4 oacc[4];
#pragma unroll
  for (int nt = 0; nt < 4; ++nt) oacc[nt] = (f32x4){0.f, 0.f, 0.f, 0.f};
#pragma unroll
  for (int vt = 0; vt < 4; ++vt) {
    __syncthreads();
    // P chunk (64 q x 128 keys) -> LDS, A-operand layout
#pragma unroll
    for (int nt = 0; nt < 4; ++nt) {
      const int col = wn * 64 + nt * 16 + l16;
#pragma unroll
      for (int r = 0; r < 4; ++r) {
        const int row = rbase + r;
        Pp[row * 128 + (((col >> 3) ^ (row & 15)) << 3) + (col & 7)] =
            f2bf(s[vt][nt][r]);
      }
    }
    // V chunk: vT[d 0..128)[keys vt*128..+128)
#pragma unroll
    for (int i = 0; i < 4; ++i) {
      int row = i * 32 + srow;
      gl16(vT + ((size_t)b * 128 + row) * 512 + vt * 128 +
               ((slc ^ (row & 15)) << 3),
           Ub + i * 4096 + wave * 512);
    }
    __syncthreads();
#pragma unroll
    for (int kk = 0; kk < 4; ++kk) {
      const int prow = wm * 16 + l16;
      short8 pa = *(const short8*)&Pp[prow * 128 + (((kk * 4 + quad) ^ (prow & 15)) << 3)];
#pragma unroll
      for (int nt = 0; nt < 4; ++nt) {
        int rr = wn * 64 + nt * 16 + l16;
        short8 vb = *(const short8*)&Ub[rr * 128 + (((kk * 4 + quad) ^ (rr & 15)) << 3)];
        oacc[nt] = MFMA(pa, vb, oacc[nt], 0, 0, 0);
      }
    }
  }
#pragma unroll
  for (int nt = 0; nt < 4; ++nt) {
    const int col = wn * 64 + nt * 16 + l16;
#pragma unroll
    for (int r = 0; r < 4; ++r)
      agg[(tok0 + rbase + r) * 128 + col] = f2bf(oacc[nt][r] * linv[r]);
  }
}

// ---------------- x-GEMM (128x128) + fused heads, pipelined 32-K tiles ----------------
__global__ __launch_bounds__(256, 2) void xh_gemm(
    const unsigned short* __restrict__ enc, const unsigned short* __restrict__ agg,
    const unsigned short* __restrict__ WpT, const float* __restrict__ bp,
    const unsigned short* __restrict__ WaCrT, float* __restrict__ logits,
    float* __restrict__ value) {
  __shared__ unsigned short sm[16384];   // staging: A [0,8192) B [8192,16384); then x-tile
  unsigned short* Asr = sm;
  unsigned short* Bsr = sm + 8192;
  const int tid = threadIdx.x, lane = tid & 63, wave = tid >> 6;
  const int quad = lane >> 4, l16 = lane & 15;
  const int wm = wave & 1, wn = wave >> 1;
  const int bm = blockIdx.y * 128, bn = blockIdx.x * 128;
  const int sr4 = tid >> 2, sl4 = tid & 3;

  f32x4 acc[4][4];
#pragma unroll
  for (int i = 0; i < 4; ++i)
#pragma unroll
    for (int j = 0; j < 4; ++j) acc[i][j] = (f32x4){0.f, 0.f, 0.f, 0.f};

  auto stage = [&](int t, int bo) {
    const unsigned short* Ap;
    int lda, kc;
    if (t < 8) { Ap = enc; lda = 256; kc = t * 32; }
    else       { Ap = agg; lda = 128; kc = t * 32 - 256; }
#pragma unroll
    for (int i = 0; i < 2; ++i) {
      int row = i * 64 + sr4;
      int sw = (sl4 ^ (row & 3)) << 3;
      gl16(Ap + (size_t)(bm + row) * lda + kc + sw,
           Asr + bo + i * 2048 + wave * 512);
      gl16(WpT + (size_t)(bn + row) * 384 + t * 32 + sw,
           Bsr + bo + i * 2048 + wave * 512);
    }
  };

  stage(0, 0);
  __syncthreads();
#pragma unroll 12
  for (int t = 0; t < 12; ++t) {
    if (t < 11) stage(t + 1, ((t + 1) & 1) * 4096);
    const int bo = (t & 1) * 4096;
    short8 af[4], bf[4];
#pragma unroll
    for (int mi = 0; mi < 4; ++mi) {
      int row = wm * 64 + mi * 16 + l16;
      af[mi] = *(const short8*)&Asr[bo + row * 32 + ((quad ^ (row & 3)) << 3)];
    }
#pragma unroll
    for (int ni = 0; ni < 4; ++ni) {
      int row = wn * 64 + ni * 16 + l16;
      bf[ni] = *(const short8*)&Bsr[bo + row * 32 + ((quad ^ (row & 3)) << 3)];
    }
#pragma unroll
    for (int mi = 0; mi < 4; ++mi)
#pragma unroll
      for (int ni = 0; ni < 4; ++ni)
        acc[mi][ni] = MFMA(af[mi], bf[ni], acc[mi][ni], 0, 0, 0);
    __syncthreads();
  }

#pragma unroll
  for (int mi = 0; mi < 4; ++mi) {
    const int row = wm * 64 + mi * 16 + quad * 4;
#pragma unroll
    for (int ni = 0; ni < 4; ++ni) {
      const int colc = wn * 64 + ni * 16 + l16;
      const float bv = bp[bn + colc];
#pragma unroll
      for (int r = 0; r < 4; ++r) {
        float v = fmaxf(acc[mi][ni][r] + bv, 0.f);
        sm[(row + r) * 128 + (((colc >> 3) ^ ((row + r) & 15)) << 3) + (colc & 7)] =
            f2bf(v);
      }
    }
  }
  __syncthreads();

  f32x4 h[2][2];
#pragma unroll
  for (int i = 0; i < 2; ++i)
#pragma unroll
    for (int j = 0; j < 2; ++j) h[i][j] = (f32x4){0.f, 0.f, 0.f, 0.f};
#pragma unroll
  for (int kc = 0; kc < 4; ++kc) {
    short8 xa[2], wb[2];
#pragma unroll
    for (int hm = 0; hm < 2; ++hm) {
      int row = wave * 32 + hm * 16 + l16;
      xa[hm] = *(const short8*)&sm[row * 128 + (((kc * 4 + quad) ^ (row & 15)) << 3)];
    }
#pragma unroll
    for (int hn = 0; hn < 2; ++hn)
      wb[hn] = ld8(WaCrT + (size_t)(hn * 16 + l16) * 256 + bn + kc * 32 + quad * 8);
#pragma unroll
    for (int hm = 0; hm < 2; ++hm)
#pragma unroll
      for (int hn = 0; hn < 2; ++hn)
        h[hm][hn] = MFMA(xa[hm], wb[hn], h[hm][hn], 0, 0, 0);
  }
#pragma unroll
  for (int hm = 0; hm < 2; ++hm) {
#pragma unroll
    for (int hn = 0; hn < 2; ++hn) {
      const int n = hn * 16 + l16;
#pragma unroll
      for (int r = 0; r < 4; ++r) {
        const int grow = bm + wave * 32 + hm * 16 + quad * 4 + r;
        if (n < 16)
          atomicAdd(&logits[(size_t)grow * 16 + n], h[hm][hn][r]);
        else if (n == 16)
          atomicAdd(&value[grow], h[hm][hn][r]);
      }
    }
  }
}

// ---------------------------------------------------------------------------
extern "C" void kernel_launch(void* const* d_in, const int* in_sizes, int n_in,
                              void* d_out, int out_size, void* d_ws,
                              size_t ws_size, hipStream_t stream) {
  const float* obs = (const float*)d_in[0];
  const float* We = (const float*)d_in[2];
  const float* be = (const float*)d_in[3];
  const float* Wc = (const float*)d_in[4];
  const float* bc = (const float*)d_in[5];
  const float* Wn = (const float*)d_in[6];
  const float* bn = (const float*)d_in[7];
  const float* Wb = (const float*)d_in[8];
  const float* bb = (const float*)d_in[9];
  const float* Wi = (const float*)d_in[10];
  const float* bi = (const float*)d_in[11];
  const float* Wq = (const float*)d_in[12];
  const float* bq = (const float*)d_in[13];
  const float* Wk = (const float*)d_in[14];
  const float* bk = (const float*)d_in[15];
  const float* Wv = (const float*)d_in[16];
  const float* bv = (const float*)d_in[17];
  const float* Wp = (const float*)d_in[18];
  const float* bp = (const float*)d_in[19];
  const float* Wa = (const float*)d_in[20];
  const float* ba = (const float*)d_in[21];
  const float* Wcr = (const float*)d_in[22];
  const float* bcr = (const float*)d_in[23];

  char* base = (char*)d_ws;
  unsigned short* enc_bf = (unsigned short*)(base);              // 16.78 MB
  unsigned short* As     = (unsigned short*)(base + 16777216);   // 16.78 MB
  unsigned short* Bs     = (unsigned short*)(base + 33554432);   // 16.78 MB
  unsigned short* obsagg = (unsigned short*)(base + 50331648);   // 8.39 MB (obs_bf -> agg)
  unsigned short* vT     = (unsigned short*)(base + 58720256);   // 8.39 MB
  unsigned short* WeT    = (unsigned short*)(base + 67239936);   // 64 KB
  unsigned short* Wqkv   = (unsigned short*)(base + 67305472);   // 192 KB
  unsigned short* WpT    = (unsigned short*)(base + 67633152);   // 192 KB
  unsigned short* WaCrT  = (unsigned short*)(base + 67829760);   // 16 KB
  float* bqkv            = (float*)(base + 67846656);            // 1.5 KB

  float* logits = (float*)d_out;
  float* value = (float*)d_out + 524288;

  prep_all<<<4906, 256, 0, stream>>>(obs, We, Wq, Wk, Wv, Wp, Wc, Wn, Wb, bc,
                                     bn, bb, Wa, Wcr, ba, bcr, bq, bk, bv, WeT,
                                     Wqkv, WpT, WaCrT, bqkv, obsagg, As, Bs,
                                     logits, value);
  encqkv<<<512, 256, 0, stream>>>(obsagg, WeT, be, Wi, bi, Wqkv, bqkv, enc_bf,
                                  As, Bs, vT);
  flash4b<<<512, 512, 0, stream>>>(As, Bs, vT, obsagg);
  xh_gemm<<<dim3(2, 256), 256, 0, stream>>>(enc_bf, obsagg, WpT, bp, WaCrT,
                                            logits, value);
}

// Round 4
// 185.684 us; speedup vs baseline: 1.0036x; 1.0036x over previous
//
#include <hip/hip_runtime.h>
#include <math.h>

// ---------------------------------------------------------------------------
// HADCommNetwork forward — fused enc+qkv, composite weights, fat-tile flash.
// B=64, N=512, OBS=128, H=256, M=128, ACT=16, T=32768.
// Identity: msg has no activation and only feeds K,V =>
//   K = enc@(Wm·Wk)+(bm·Wk+bk), V = enc@(Wm·Wv)+(bm·Wv+bv)  (msg eliminated).
// r12 (resubmit after infra timeout): xh_gemm -> 64-row x full-N blocks,
// in-register head combine, plain stores (no logits atomics, no logits/value
// init in prep; prep 4906->2730 blocks). 4 launches:
//   prep_all(+wprod) | encqkv | flash4b | x+heads
// ---------------------------------------------------------------------------

typedef __attribute__((ext_vector_type(8))) short short8;
typedef __attribute__((ext_vector_type(4))) float f32x4;

#define RSQRT_D 0.08838834764831843f  // 1/sqrt(128)
#define MFMA __builtin_amdgcn_mfma_f32_16x16x32_bf16

__device__ __forceinline__ unsigned short f2bf(float f) {
  union { float f; unsigned u; } v; v.f = f;
  return (unsigned short)((v.u + 0x7FFFu + ((v.u >> 16) & 1u)) >> 16);
}
__device__ __forceinline__ float bf2f(unsigned short h) {
  union { unsigned u; float f; } v; v.u = ((unsigned)h) << 16;
  return v.f;
}
__device__ __forceinline__ unsigned pack2(float a, float b) {
  return (unsigned)f2bf(a) | ((unsigned)f2bf(b) << 16);
}
__device__ __forceinline__ short8 ld8(const unsigned short* p) {
  return *(const short8*)p;
}
__device__ __forceinline__ void gl16(const unsigned short* g,
                                     unsigned short* l) {
  __builtin_amdgcn_global_load_lds(
      (const __attribute__((address_space(1))) unsigned int*)(const void*)g,
      (__attribute__((address_space(3))) unsigned int*)(void*)l, 16, 0, 0);
}

// ---------------- prep: weights + obs + composite wprod ----------------
// blocks 0..672: weight transposes/packs (172160 elems)
// blocks 673..2720: obs prep (16 tokens/block)
// blocks 2721..2728: composite Wqkv rows 128..383 via MFMA from f32 sources
// block  2729: bqkv rows 128..383 tail
__global__ __launch_bounds__(256) void prep_all(
    const float* __restrict__ obs, const float* __restrict__ We,
    const float* __restrict__ Wq, const float* __restrict__ Wk,
    const float* __restrict__ Wv, const float* __restrict__ Wp,
    const float* __restrict__ Wc, const float* __restrict__ Wn,
    const float* __restrict__ Wb, const float* __restrict__ bc,
    const float* __restrict__ bn, const float* __restrict__ bb,
    const float* __restrict__ Wa, const float* __restrict__ Wcr,
    const float* __restrict__ bq, const float* __restrict__ bk,
    const float* __restrict__ bv, unsigned short* __restrict__ WeT,
    unsigned short* __restrict__ Wqkv, unsigned short* __restrict__ WpT,
    unsigned short* __restrict__ WaCrT, float* __restrict__ bqkv,
    unsigned short* __restrict__ obs_bf, unsigned short* __restrict__ As,
    unsigned short* __restrict__ Bs) {
  const int bid = blockIdx.x, tid = threadIdx.x;
  if (bid < 673) {
    int idx = bid * 256 + tid;
    if (idx < 32768) {                 // WeT[n 256][k 128]
      int n = idx >> 7, k = idx & 127;
      WeT[idx] = f2bf(We[k * 256 + n]);
    } else if (idx < 65536) {          // Wqkv rows 0..127: WqT[n 128][k 256]
      int i = idx - 32768;
      int n = i >> 8, k = i & 255;
      Wqkv[i] = f2bf(Wq[k * 128 + n]);
    } else if (idx < 163840) {         // WpT[n 256][k 384]
      int i = idx - 65536;
      int n = i / 384, k = i - n * 384;
      WpT[i] = f2bf(Wp[k * 256 + n]);
    } else if (idx < 172032) {         // WaCrT[32][256]
      int i = idx - 163840;
      int n = i >> 8, k = i & 255;
      float v = (n < 16) ? Wa[k * 16 + n] : (n == 16) ? Wcr[k] : 0.f;
      WaCrT[i] = f2bf(v);
    } else if (idx < 172160) {
      int i = idx - 172032;
      bqkv[i] = bq[i];
    }
  } else if (bid < 2721) {
    // obs prep: 16 tokens/block (4 per wave)
    const int wave = tid >> 6, lane = tid & 63;
    const int t0 = (bid - 673) * 16 + wave * 4;
#pragma unroll
    for (int it = 0; it < 4; ++it) {
      int t = t0 + it;
      const float* row = obs + (size_t)t * 128;
      float2 o = *(const float2*)(row + lane * 2);
      float s2 = o.x * o.x + o.y * o.y;
#pragma unroll
      for (int off = 1; off < 64; off <<= 1) s2 += __shfl_xor(s2, off);
      float inv = 1.f / (sqrtf(s2) + 1e-8f);
      ((unsigned*)obs_bf)[(size_t)t * 64 + lane] = pack2(o.x, o.y);
      ((unsigned*)As)[(size_t)t * 128 + 64 + lane] =
          pack2(o.x * 0.5f * inv, o.y * 0.5f * inv);
      ((unsigned*)Bs)[(size_t)t * 128 + 64 + lane] =
          pack2(o.x * inv, o.y * inv);
    }
  } else if (bid < 2729) {
    // composite Wqkv rows 128..383 = Wkv @ Wm^T via MFMA, f32 sources inline
    const int wb = bid - 2721;
    const int lane = tid & 63, wave = tid >> 6;
    const int quad = lane >> 4, l16 = lane & 15;
    const int r0 = wb * 32;
    f32x4 acc[2][4];
#pragma unroll
    for (int i = 0; i < 2; ++i)
#pragma unroll
      for (int j = 0; j < 4; ++j) acc[i][j] = (f32x4){0.f, 0.f, 0.f, 0.f};
#pragma unroll
    for (int kc = 0; kc < 4; ++kc) {
      short8 af[2], bf[4];
#pragma unroll
      for (int i = 0; i < 2; ++i) {
        int n = r0 + i * 16 + l16;
        const float* src = (n < 128) ? (Wk + n) : (Wv + (n - 128));
        short8 v;
#pragma unroll
        for (int e = 0; e < 8; ++e)
          v[e] = (short)f2bf(src[(size_t)(kc * 32 + quad * 8 + e) * 128]);
        af[i] = v;
      }
#pragma unroll
      for (int j = 0; j < 4; ++j) {
        int h = wave * 64 + j * 16 + l16;
        int m0 = kc * 32 + quad * 8;
        const float* p = (m0 < 32)   ? (Wc + (size_t)h * 32 + m0)
                       : (m0 < 96)   ? (Wn + (size_t)h * 64 + (m0 - 32))
                                     : (Wb + (size_t)h * 32 + (m0 - 96));
        short8 v;
#pragma unroll
        for (int e = 0; e < 8; ++e) v[e] = (short)f2bf(p[e]);
        bf[j] = v;
      }
#pragma unroll
      for (int i = 0; i < 2; ++i)
#pragma unroll
        for (int j = 0; j < 4; ++j)
          acc[i][j] = MFMA(af[i], bf[j], acc[i][j], 0, 0, 0);
    }
#pragma unroll
    for (int i = 0; i < 2; ++i) {
      const int row = r0 + i * 16 + quad * 4;
#pragma unroll
      for (int j = 0; j < 4; ++j) {
        const int col = wave * 64 + j * 16 + l16;
#pragma unroll
        for (int r = 0; r < 4; ++r)
          Wqkv[(size_t)(128 + row + r) * 256 + col] = f2bf(acc[i][j][r]);
      }
    }
  } else {
    // bqkv rows 128..383 (bf16-rounded Wkv to match MFMA-path numerics)
    int i = tid;
    float acc = (i < 128) ? bk[i] : bv[i - 128];
    for (int m = 0; m < 128; ++m) {
      float bmv = (m < 32) ? bc[m] : (m < 96) ? bn[m - 32] : bb[m - 96];
      float w = (i < 128) ? Wk[(size_t)m * 128 + i]
                          : Wv[(size_t)m * 128 + (i - 128)];
      acc += bmv * bf2f(f2bf(w));
    }
    bqkv[128 + i] = acc;
  }
}

// ---------------- encqkv: fused enc GEMM + imp + qkv GEMM ----------------
// 512 blocks x 256 thr. bm0 = bid*64 (64-row tile).
// Phase 1: enc[64][256] = relu(obs@We+be), A/B staged single-shot (80KB).
// Phase 2: acc -> enc_lds (Pp-swizzle, qkv A-operand) + global enc + imp (LDS).
// Phase 3: 3 N-tiles of qkv from enc_lds, Wqkv streamed 64-K dbuf chunks.
__global__ __launch_bounds__(256, 2) void encqkv(
    const unsigned short* __restrict__ obs_bf,
    const unsigned short* __restrict__ WeT, const float* __restrict__ be,
    const float* __restrict__ Wi, const float* __restrict__ bi,
    const unsigned short* __restrict__ Wqkv, const float* __restrict__ bqkv,
    unsigned short* __restrict__ enc, unsigned short* __restrict__ As,
    unsigned short* __restrict__ Bs, unsigned short* __restrict__ vT) {
  __shared__ char smem[81920];
  unsigned short* Asr = (unsigned short*)smem;             // ph1: [64][128] 16KB
  unsigned short* Bsr = (unsigned short*)(smem + 16384);   // ph1: [256][128] 64KB
  unsigned short* encl = (unsigned short*)smem;            // ph2+: 2x[64][128] 32KB
  unsigned short* Bq = (unsigned short*)(smem + 32768);    // ph3: dbuf 2x16KB
  float* imp_lds = (float*)(smem + 65536);                 // 64 floats
  const int tid = threadIdx.x, lane = tid & 63, wave = tid >> 6;
  const int quad = lane >> 4, l16 = lane & 15;
  const int bm0 = blockIdx.x * 64;

  // ---- phase 1: stage obs tile (4 rounds) + full WeT (16 rounds) ----
#pragma unroll
  for (int it = 0; it < 4; ++it) {
    int c = it * 256 + tid;
    int row = c >> 4, ch = c & 15;
    gl16(obs_bf + (size_t)(bm0 + row) * 128 + ((ch ^ (row & 15)) << 3),
         Asr + it * 2048 + wave * 512);
  }
#pragma unroll
  for (int it = 0; it < 16; ++it) {
    int c = it * 256 + tid;
    int row = c >> 4, ch = c & 15;
    gl16(WeT + (size_t)row * 128 + ((ch ^ (row & 15)) << 3),
         Bsr + it * 2048 + wave * 512);
  }
  __syncthreads();

  f32x4 acc[4][4];
#pragma unroll
  for (int i = 0; i < 4; ++i)
#pragma unroll
    for (int j = 0; j < 4; ++j) acc[i][j] = (f32x4){0.f, 0.f, 0.f, 0.f};
#pragma unroll
  for (int ks = 0; ks < 4; ++ks) {
    short8 af[4], bf[4];
#pragma unroll
    for (int mi = 0; mi < 4; ++mi) {
      int row = mi * 16 + l16;
      af[mi] = *(const short8*)&Asr[row * 128 + (((ks * 4 + quad) ^ (row & 15)) << 3)];
    }
#pragma unroll
    for (int ni = 0; ni < 4; ++ni) {
      int row = wave * 64 + ni * 16 + l16;
      bf[ni] = *(const short8*)&Bsr[row * 128 + (((ks * 4 + quad) ^ (row & 15)) << 3)];
    }
#pragma unroll
    for (int mi = 0; mi < 4; ++mi)
#pragma unroll
      for (int ni = 0; ni < 4; ++ni)
        acc[mi][ni] = MFMA(af[mi], bf[ni], acc[mi][ni], 0, 0, 0);
  }
  __syncthreads();  // all Asr/Bsr reads complete; LDS reusable

  if (tid < 64) imp_lds[tid] = 0.f;
  __syncthreads();  // imp zeroed before atomics

  // ---- phase 3 prefetch: first Wqkv chunk (ct=0, kt=0) into Bq[0] ----
  {
#pragma unroll
    for (int i = 0; i < 4; ++i) {
      int row = i * 32 + (tid >> 3);
      gl16(Wqkv + (size_t)row * 256 + (((tid & 7) ^ (row & 7)) << 3),
           Bq + i * 2048 + wave * 512);
    }
  }

  // ---- phase 2: acc -> enc_lds + global enc + block-local imp ----
  const float bi0 = bi[0];
#pragma unroll
  for (int mi = 0; mi < 4; ++mi) {
    const int rowl = mi * 16 + quad * 4;
    float ip[4] = {0.f, 0.f, 0.f, 0.f};
#pragma unroll
    for (int ni = 0; ni < 4; ++ni) {
      const int col = wave * 64 + ni * 16 + l16;
      const float bvv = be[col], wv = Wi[col];
      const int kh = col >> 7, ic = col & 127;
#pragma unroll
      for (int r = 0; r < 4; ++r) {
        const int row = rowl + r;
        float v = fmaxf(acc[mi][ni][r] + bvv, 0.f);
        enc[(size_t)(bm0 + row) * 256 + col] = f2bf(v);
        encl[kh * 8192 + row * 128 + (((ic >> 3) ^ (row & 15)) << 3) + (ic & 7)] =
            f2bf(v);
        ip[r] += v * wv;
      }
    }
#pragma unroll
    for (int r = 0; r < 4; ++r) {
#pragma unroll
      for (int off = 1; off < 16; off <<= 1) ip[r] += __shfl_xor(ip[r], off);
    }
    if (l16 == 0) {
#pragma unroll
      for (int r = 0; r < 4; ++r) atomicAdd(&imp_lds[rowl + r], ip[r]);
    }
  }
  __syncthreads();  // encl + imp ready; Bq[0] landed (vmcnt drained)

  // ---- phase 3: qkv = enc_lds @ Wqkv^T, 3 N-tiles, 64-K dbuf chunks ----
  const int wm = wave & 1, wn = wave >> 1;
  for (int ct = 0; ct < 3; ++ct) {
    f32x4 a2[2][4];
#pragma unroll
    for (int i = 0; i < 2; ++i)
#pragma unroll
      for (int j = 0; j < 4; ++j) a2[i][j] = (f32x4){0.f, 0.f, 0.f, 0.f};
#pragma unroll
    for (int kt = 0; kt < 4; ++kt) {
      // prefetch next chunk (next kt, or next ct's kt=0)
      if (kt < 3 || ct < 2) {
        const int nct = (kt < 3) ? ct : ct + 1;
        const int nkt = (kt < 3) ? kt + 1 : 0;
        const int nbo = ((kt + 1) & 1) * 8192;
#pragma unroll
        for (int i = 0; i < 4; ++i) {
          int row = i * 32 + (tid >> 3);
          gl16(Wqkv + (size_t)(nct * 128 + row) * 256 + nkt * 64 +
                   (((tid & 7) ^ (row & 7)) << 3),
               Bq + nbo + i * 2048 + wave * 512);
        }
      }
      const int bo = (kt & 1) * 8192;
#pragma unroll
      for (int ks2 = 0; ks2 < 2; ++ks2) {
        const int kc = kt * 2 + ks2;
        const int kh = kc >> 2, c4 = kc & 3;
        short8 af2[2], bf2[4];
#pragma unroll
        for (int mi = 0; mi < 2; ++mi) {
          int row = wm * 32 + mi * 16 + l16;
          af2[mi] = *(const short8*)&encl[kh * 8192 + row * 128 +
                                          (((c4 * 4 + quad) ^ (row & 15)) << 3)];
        }
#pragma unroll
        for (int ni = 0; ni < 4; ++ni) {
          int row = wn * 64 + ni * 16 + l16;
          bf2[ni] = *(const short8*)&Bq[bo + row * 64 +
                                        (((ks2 * 4 + quad) ^ (row & 7)) << 3)];
        }
#pragma unroll
        for (int mi = 0; mi < 2; ++mi)
#pragma unroll
          for (int ni = 0; ni < 4; ++ni)
            a2[mi][ni] = MFMA(af2[mi], bf2[ni], a2[mi][ni], 0, 0, 0);
      }
      __syncthreads();
    }

    // epilogue for this N-tile
#pragma unroll
    for (int mi = 0; mi < 2; ++mi) {
      const int rowl = wm * 32 + mi * 16 + quad * 4;
      const int rowb = bm0 + rowl;
      float sg[4];
      if (ct < 2) {
        const float mult = (ct == 0) ? RSQRT_D : 1.0f;
#pragma unroll
        for (int r = 0; r < 4; ++r)
          sg[r] = mult / (1.f + __expf(-(imp_lds[rowl + r] + bi0)));
      }
#pragma unroll
      for (int ni = 0; ni < 4; ++ni) {
        const int col = wn * 64 + ni * 16 + l16;
        const float bvv = bqkv[ct * 128 + col];
        if (ct == 0) {
#pragma unroll
          for (int r = 0; r < 4; ++r)
            As[(size_t)(rowb + r) * 256 + col] =
                f2bf((a2[mi][ni][r] + bvv) * sg[r]);
        } else if (ct == 1) {
#pragma unroll
          for (int r = 0; r < 4; ++r)
            Bs[(size_t)(rowb + r) * 256 + col] =
                f2bf((a2[mi][ni][r] + bvv) * sg[r]);
        } else {
          uint2 o;
          o.x = pack2(a2[mi][ni][0] + bvv, a2[mi][ni][1] + bvv);
          o.y = pack2(a2[mi][ni][2] + bvv, a2[mi][ni][3] + bvv);
          *(uint2*)(vT + ((size_t)(rowb >> 9) * 128 + col) * 512 +
                    (rowb & 511)) = o;
        }
      }
    }
  }
}

// ---------------- flash4b: q-tile 64, 512 threads, single-pass softmax ----------------
// 512 blocks: b = id&63 (XCD-local), qt = id>>6 (8 q-tiles of 64).
// 8 waves: wm = wave&3 (16-row group), wn = wave>>2 (64-key half of staged 128).
// QK^T: 16 pipelined chunks (128 keys x 64 dims, 16 KB), dbuf in same 32 KB Ub.
__global__ __launch_bounds__(512, 4) void flash4b(
    const unsigned short* __restrict__ As, const unsigned short* __restrict__ Bs,
    const unsigned short* __restrict__ vT, unsigned short* __restrict__ agg) {
  __shared__ unsigned short Ub[16384];  // 32 KB
  __shared__ unsigned short Pp[8192];   // 16 KB (64 q x 128 keys)
  __shared__ float redm[2][64];
  __shared__ float reds[2][64];
  const int tid = threadIdx.x, lane = tid & 63, wave = tid >> 6;
  const int quad = lane >> 4, l16 = lane & 15;
  const int wm = wave & 3, wn = wave >> 2;
  const int b = blockIdx.x & 63;
  const int qt = blockIdx.x >> 6;
  const size_t tok0 = (size_t)b * 512 + qt * 64;
  const int srow = tid >> 4, slc = tid & 15;  // PV staging: 32 rows/iter
  const int qr8 = tid >> 3, ql8 = tid & 7;    // QK^T staging: 64 rows/round

  short8 af[8];
#pragma unroll
  for (int kc = 0; kc < 8; ++kc)
    af[kc] = ld8(As + (tok0 + wm * 16 + l16) * 256 + kc * 32 + quad * 8);

  f32x4 s[4][4];
#pragma unroll
  for (int kt = 0; kt < 4; ++kt)
#pragma unroll
    for (int nt = 0; nt < 4; ++nt) s[kt][nt] = (f32x4){0.f, 0.f, 0.f, 0.f};

  // ---- QK^T over all 512 keys: pipelined chunk c = (kt<<2)|dq ----
  auto qstage = [&](int c) {
    const int kt_ = c >> 2, dq_ = c & 3;
#pragma unroll
    for (int r2 = 0; r2 < 2; ++r2) {
      int row = r2 * 64 + qr8;
      gl16(Bs + ((size_t)b * 512 + kt_ * 128 + row) * 256 + dq_ * 64 +
               ((ql8 ^ (row & 7)) << 3),
           Ub + (c & 1) * 8192 + r2 * 4096 + wave * 512);
    }
  };
  qstage(0);
  __syncthreads();
#pragma unroll 16
  for (int c = 0; c < 16; ++c) {
    if (c < 15) qstage(c + 1);
    const int kt = c >> 2, dq = c & 3;
    const int ub0 = (c & 1) * 8192;
#pragma unroll
    for (int kk2 = 0; kk2 < 2; ++kk2) {
      short8 bfr[4];
#pragma unroll
      for (int nt = 0; nt < 4; ++nt) {
        int rr = wn * 64 + nt * 16 + l16;
        bfr[nt] = *(const short8*)&Ub[ub0 + rr * 64 +
                                      (((kk2 * 2 + quad) ^ (rr & 7)) << 3)];
      }
#pragma unroll
      for (int nt = 0; nt < 4; ++nt)
        s[kt][nt] = MFMA(af[dq * 2 + kk2], bfr[nt], s[kt][nt], 0, 0, 0);
    }
    __syncthreads();
  }

  // ---- exact softmax (rows = wm*16 + quad*4 + r) ----
  const int rbase = wm * 16 + quad * 4;
  float mt[4];
#pragma unroll
  for (int r = 0; r < 4; ++r) {
    float mv = -1e30f;
#pragma unroll
    for (int kt = 0; kt < 4; ++kt)
#pragma unroll
      for (int nt = 0; nt < 4; ++nt) mv = fmaxf(mv, s[kt][nt][r]);
#pragma unroll
    for (int off = 1; off < 16; off <<= 1) mv = fmaxf(mv, __shfl_xor(mv, off));
    mt[r] = mv;
  }
  if (l16 == 0) {
#pragma unroll
    for (int r = 0; r < 4; ++r) redm[wn][rbase + r] = mt[r];
  }
  __syncthreads();
  float lsum[4];
#pragma unroll
  for (int r = 0; r < 4; ++r) {
    float mfull = fmaxf(mt[r], redm[1 ^ wn][rbase + r]);
    float sum = 0.f;
#pragma unroll
    for (int kt = 0; kt < 4; ++kt)
#pragma unroll
      for (int nt = 0; nt < 4; ++nt) {
        float p = __expf(s[kt][nt][r] - mfull);
        s[kt][nt][r] = p;
        sum += p;
      }
#pragma unroll
    for (int off = 1; off < 16; off <<= 1) sum += __shfl_xor(sum, off);
    lsum[r] = sum;
  }
  if (l16 == 0) {
#pragma unroll
    for (int r = 0; r < 4; ++r) reds[wn][rbase + r] = lsum[r];
  }
  __syncthreads();
  float linv[4];
#pragma unroll
  for (int r = 0; r < 4; ++r)
    linv[r] = 1.0f / (lsum[r] + reds[1 ^ wn][rbase + r]);

  // ---- PV over 4 key chunks ----
  f32x4 oacc[4];
#pragma unroll
  for (int nt = 0; nt < 4; ++nt) oacc[nt] = (f32x4){0.f, 0.f, 0.f, 0.f};
#pragma unroll
  for (int vt = 0; vt < 4; ++vt) {
    __syncthreads();
    // P chunk (64 q x 128 keys) -> LDS, A-operand layout
#pragma unroll
    for (int nt = 0; nt < 4; ++nt) {
      const int col = wn * 64 + nt * 16 + l16;
#pragma unroll
      for (int r = 0; r < 4; ++r) {
        const int row = rbase + r;
        Pp[row * 128 + (((col >> 3) ^ (row & 15)) << 3) + (col & 7)] =
            f2bf(s[vt][nt][r]);
      }
    }
    // V chunk: vT[d 0..128)[keys vt*128..+128)
#pragma unroll
    for (int i = 0; i < 4; ++i) {
      int row = i * 32 + srow;
      gl16(vT + ((size_t)b * 128 + row) * 512 + vt * 128 +
               ((slc ^ (row & 15)) << 3),
           Ub + i * 4096 + wave * 512);
    }
    __syncthreads();
#pragma unroll
    for (int kk = 0; kk < 4; ++kk) {
      const int prow = wm * 16 + l16;
      short8 pa = *(const short8*)&Pp[prow * 128 + (((kk * 4 + quad) ^ (prow & 15)) << 3)];
#pragma unroll
      for (int nt = 0; nt < 4; ++nt) {
        int rr = wn * 64 + nt * 16 + l16;
        short8 vb = *(const short8*)&Ub[rr * 128 + (((kk * 4 + quad) ^ (rr & 15)) << 3)];
        oacc[nt] = MFMA(pa, vb, oacc[nt], 0, 0, 0);
      }
    }
  }
#pragma unroll
  for (int nt = 0; nt < 4; ++nt) {
    const int col = wn * 64 + nt * 16 + l16;
#pragma unroll
    for (int r = 0; r < 4; ++r)
      agg[(tok0 + rbase + r) * 128 + col] = f2bf(oacc[nt][r] * linv[r]);
  }
}

// ---------------- x-GEMM: 64-row x full-N(256) blocks + in-reg heads ----------------
// 512 blocks x 256 thr. Each block: x[64][256] = relu([enc,agg]@Wp + bp),
// kept in LDS; heads computed over full k=256 in-register; PLAIN stores of
// logits = ba + h and value = bcr + h (no atomics, no init kernel).
__global__ __launch_bounds__(256, 2) void xh_gemm(
    const unsigned short* __restrict__ enc, const unsigned short* __restrict__ agg,
    const unsigned short* __restrict__ WpT, const float* __restrict__ bp,
    const unsigned short* __restrict__ WaCrT, const float* __restrict__ ba,
    const float* __restrict__ bcr, float* __restrict__ logits,
    float* __restrict__ value) {
  __shared__ unsigned short sm[32768];  // 64 KB: stage A 2x4KB | B 2x16KB; then x 32KB
  const int tid = threadIdx.x, lane = tid & 63, wave = tid >> 6;
  const int quad = lane >> 4, l16 = lane & 15;
  const int bm = blockIdx.x * 64;
  const int sr4 = tid >> 2, sl4 = tid & 3;

  f32x4 acc[4][4];
#pragma unroll
  for (int i = 0; i < 4; ++i)
#pragma unroll
    for (int j = 0; j < 4; ++j) acc[i][j] = (f32x4){0.f, 0.f, 0.f, 0.f};

  auto stage = [&](int t, int half) {
    const unsigned short* Ap;
    int lda, kc;
    if (t < 8) { Ap = enc; lda = 256; kc = t * 32; }
    else       { Ap = agg; lda = 128; kc = t * 32 - 256; }
    // A: 64 rows x 32 cols (4 KB, one round)
    {
      int row = sr4;
      int sw = (sl4 ^ (row & 3)) << 3;
      gl16(Ap + (size_t)(bm + row) * lda + kc + sw,
           sm + half * 2048 + wave * 512);
    }
    // B: 256 rows x 32 cols (16 KB, four rounds)
#pragma unroll
    for (int i = 0; i < 4; ++i) {
      int row = i * 64 + sr4;
      int sw = (sl4 ^ (row & 3)) << 3;
      gl16(WpT + (size_t)row * 384 + t * 32 + sw,
           sm + 4096 + half * 8192 + i * 2048 + wave * 512);
    }
  };

  stage(0, 0);
  __syncthreads();
#pragma unroll 12
  for (int t = 0; t < 12; ++t) {
    if (t < 11) stage(t + 1, (t + 1) & 1);
    const int abo = (t & 1) * 2048, bbo = 4096 + (t & 1) * 8192;
    short8 af[4], bf[4];
#pragma unroll
    for (int mi = 0; mi < 4; ++mi) {
      int row = mi * 16 + l16;
      af[mi] = *(const short8*)&sm[abo + row * 32 + ((quad ^ (row & 3)) << 3)];
    }
#pragma unroll
    for (int ni = 0; ni < 4; ++ni) {
      int row = wave * 64 + ni * 16 + l16;
      bf[ni] = *(const short8*)&sm[bbo + row * 32 + ((quad ^ (row & 3)) << 3)];
    }
#pragma unroll
    for (int mi = 0; mi < 4; ++mi)
#pragma unroll
      for (int ni = 0; ni < 4; ++ni)
        acc[mi][ni] = MFMA(af[mi], bf[ni], acc[mi][ni], 0, 0, 0);
    __syncthreads();
  }

  // x[64][256] -> LDS (swizzled A-operand layout for heads)
#pragma unroll
  for (int mi = 0; mi < 4; ++mi) {
    const int row0 = mi * 16 + quad * 4;
#pragma unroll
    for (int ni = 0; ni < 4; ++ni) {
      const int colc = wave * 64 + ni * 16 + l16;
      const float bv = bp[colc];
#pragma unroll
      for (int r = 0; r < 4; ++r) {
        const int row = row0 + r;
        float v = fmaxf(acc[mi][ni][r] + bv, 0.f);
        sm[row * 256 + ((((colc >> 3) ^ (row & 15))) << 3) + (colc & 7)] =
            f2bf(v);
      }
    }
  }
  __syncthreads();

  // heads: full k=256 in-register accumulation, plain stores
  f32x4 h[2];
#pragma unroll
  for (int j = 0; j < 2; ++j) h[j] = (f32x4){0.f, 0.f, 0.f, 0.f};
#pragma unroll
  for (int kc = 0; kc < 8; ++kc) {
    short8 xa;
    {
      int row = wave * 16 + l16;
      xa = *(const short8*)&sm[row * 256 + (((kc * 4 + quad) ^ (row & 15)) << 3)];
    }
#pragma unroll
    for (int hn = 0; hn < 2; ++hn) {
      short8 wb = ld8(WaCrT + (size_t)(hn * 16 + l16) * 256 + kc * 32 + quad * 8);
      h[hn] = MFMA(xa, wb, h[hn], 0, 0, 0);
    }
  }
#pragma unroll
  for (int hn = 0; hn < 2; ++hn) {
    const int n = hn * 16 + l16;
#pragma unroll
    for (int r = 0; r < 4; ++r) {
      const int grow = bm + wave * 16 + quad * 4 + r;
      if (n < 16)
        logits[(size_t)grow * 16 + n] = ba[n] + h[hn][r];
      else if (n == 16)
        value[grow] = bcr[0] + h[hn][r];
    }
  }
}

// ---------------------------------------------------------------------------
extern "C" void kernel_launch(void* const* d_in, const int* in_sizes, int n_in,
                              void* d_out, int out_size, void* d_ws,
                              size_t ws_size, hipStream_t stream) {
  const float* obs = (const float*)d_in[0];
  const float* We = (const float*)d_in[2];
  const float* be = (const float*)d_in[3];
  const float* Wc = (const float*)d_in[4];
  const float* bc = (const float*)d_in[5];
  const float* Wn = (const float*)d_in[6];
  const float* bn = (const float*)d_in[7];
  const float* Wb = (const float*)d_in[8];
  const float* bb = (const float*)d_in[9];
  const float* Wi = (const float*)d_in[10];
  const float* bi = (const float*)d_in[11];
  const float* Wq = (const float*)d_in[12];
  const float* bq = (const float*)d_in[13];
  const float* Wk = (const float*)d_in[14];
  const float* bk = (const float*)d_in[15];
  const float* Wv = (const float*)d_in[16];
  const float* bv = (const float*)d_in[17];
  const float* Wp = (const float*)d_in[18];
  const float* bp = (const float*)d_in[19];
  const float* Wa = (const float*)d_in[20];
  const float* ba = (const float*)d_in[21];
  const float* Wcr = (const float*)d_in[22];
  const float* bcr = (const float*)d_in[23];

  char* base = (char*)d_ws;
  unsigned short* enc_bf = (unsigned short*)(base);              // 16.78 MB
  unsigned short* As     = (unsigned short*)(base + 16777216);   // 16.78 MB
  unsigned short* Bs     = (unsigned short*)(base + 33554432);   // 16.78 MB
  unsigned short* obsagg = (unsigned short*)(base + 50331648);   // 8.39 MB (obs_bf -> agg)
  unsigned short* vT     = (unsigned short*)(base + 58720256);   // 8.39 MB
  unsigned short* WeT    = (unsigned short*)(base + 67239936);   // 64 KB
  unsigned short* Wqkv   = (unsigned short*)(base + 67305472);   // 192 KB
  unsigned short* WpT    = (unsigned short*)(base + 67633152);   // 192 KB
  unsigned short* WaCrT  = (unsigned short*)(base + 67829760);   // 16 KB
  float* bqkv            = (float*)(base + 67846656);            // 1.5 KB

  float* logits = (float*)d_out;
  float* value = (float*)d_out + 524288;

  prep_all<<<2730, 256, 0, stream>>>(obs, We, Wq, Wk, Wv, Wp, Wc, Wn, Wb, bc,
                                     bn, bb, Wa, Wcr, bq, bk, bv, WeT, Wqkv,
                                     WpT, WaCrT, bqkv, obsagg, As, Bs);
  encqkv<<<512, 256, 0, stream>>>(obsagg, WeT, be, Wi, bi, Wqkv, bqkv, enc_bf,
                                  As, Bs, vT);
  flash4b<<<512, 512, 0, stream>>>(As, Bs, vT, obsagg);
  xh_gemm<<<512, 256, 0, stream>>>(enc_bf, obsagg, WpT, bp, WaCrT, ba, bcr,
                                   logits, value);
}